// Round 2
// baseline (763.142 us; speedup 1.0000x reference)
//
#include <hip/hip_runtime.h>
#include <hip/hip_bf16.h>
#include <math.h>

// Problem constants (from reference)
#define NN   10000      // nodes
#define NE   320000     // edges
#define KK   10000      // input features
#define HID  128
#define KPAD 10048      // 157*64, zero-padded K for Wt
#define MT   79         // ceil(10000/128) M-tiles
#define KITERS 157      // ceil(10000/64)
#define NSPLIT 8        // K-split for GEMM grid

typedef __bf16 bf16x8 __attribute__((ext_vector_type(8)));
typedef float  f32x16 __attribute__((ext_vector_type(16)));

// ---- workspace layout (bytes), total ~16.2 MB ----
#define OFF_DINV 0u             // 40000 B (deg, then dinv in place)
#define OFF_FLAG 40960u         // 4 B (edge-index dtype flag)
#define OFF_CNT  45056u         // 40000 B int in-degree counts
#define OFF_ROW  86016u         // 40004 B rowstart[NN+1]
#define OFF_CUR  126976u        // 40000 B scatter cursors
#define OFF_ER   262144u        // 1.28 MB src (int32)
#define OFF_EC   1572864u       // 1.28 MB dst (int32)
#define OFF_CSRS 2883584u       // 1.28 MB CSR src node per slot
#define OFF_CSRW 4194304u       // 1.28 MB CSR norm weight per slot
#define OFF_H    8388608u       // 10000*128 f32 = 5.12 MB
#define OFF_WT   13631488u      // 128*10048 bf16 = 2.57 MB

__device__ inline unsigned short f2bf(float f) {
  unsigned int v = __builtin_bit_cast(unsigned int, f);
  unsigned int lsb = (v >> 16) & 1u;
  v += 0x7fffu + lsb;                 // round-to-nearest-even
  return (unsigned short)(v >> 16);
}

// ---- detect edge_index storage width: int64 => all high words zero ----
__global__ __launch_bounds__(64) void k_detect(const int* __restrict__ ei,
                                               int* __restrict__ flag) {
  int t = threadIdx.x;                 // 64 threads
  int v = ei[2*t + 1];                 // high word if int64, else a real index
  unsigned long long b = __ballot(v != 0);
  if (t == 0) flag[0] = (b == 0ull) ? 1 : 0;
}

// ---- normalize edge_index to int32 er/ec; fused weighted-degree + count ----
__global__ __launch_bounds__(256) void k_edges(const int* __restrict__ ei,
                                               const int* __restrict__ flag,
                                               const float* __restrict__ ew,
                                               int* __restrict__ er,
                                               int* __restrict__ ec,
                                               float* __restrict__ deg,
                                               int* __restrict__ cnt) {
  int e = blockIdx.x*256 + threadIdx.x;
  if (e < NE) {
    int s = flag[0];
    int r = ei[(size_t)e << s];
    int c = ei[((size_t)(NE + e)) << s];
    er[e] = r;
    ec[e] = c;
    atomicAdd(&deg[c], ew[e]);
    atomicAdd(&cnt[c], 1);
  }
}

// ---- transpose + convert + zero-pad W_conv [KK][HID] f32 -> Wt [HID][KPAD] bf16 ----
__global__ __launch_bounds__(256) void k_transpose(const float* __restrict__ W,
                                                   unsigned short* __restrict__ Wt) {
  __shared__ float t[32][33];
  const int tx = threadIdx.x, ty = threadIdx.y;
  const int bk = blockIdx.x, bn = blockIdx.y;
#pragma unroll
  for (int j = 0; j < 4; ++j) {
    int k = bk*32 + ty + j*8;
    int n = bn*32 + tx;
    float v = 0.0f;
    if (k < KK) v = W[(size_t)k*HID + n];
    t[ty + j*8][tx] = v;
  }
  __syncthreads();
#pragma unroll
  for (int j = 0; j < 4; ++j) {
    int n = bn*32 + ty + j*8;
    int k = bk*32 + tx;
    Wt[(size_t)n*KPAD + k] = f2bf(t[tx][ty + j*8]);
  }
}

// ---- deg -> dinv in place (self-loop weight 1 added) ----
__global__ __launch_bounds__(256) void k_dinv(float* __restrict__ deg) {
  int i = blockIdx.x*256 + threadIdx.x;
  if (i < NN) {
    float d = deg[i] + 1.0f;
    deg[i] = (d > 0.0f) ? (1.0f / sqrtf(d)) : 0.0f;
  }
}

// ---- single-block exclusive scan of cnt[NN] -> rowstart[NN+1], cursor copy ----
__global__ __launch_bounds__(256) void k_scan(const int* __restrict__ cnt,
                                              int* __restrict__ rowstart,
                                              int* __restrict__ cursor) {
  __shared__ int sums[256];
  const int t = threadIdx.x;
  const int CH = 40;                  // 256*40 = 10240 >= NN
  const int base = t * CH;
  int s = 0;
  for (int k = 0; k < CH; ++k) {
    int i = base + k;
    if (i < NN) s += cnt[i];
  }
  sums[t] = s;
  __syncthreads();
  // Hillis-Steele inclusive scan over per-thread sums
  for (int off = 1; off < 256; off <<= 1) {
    int add = (t >= off) ? sums[t - off] : 0;
    __syncthreads();
    sums[t] += add;
    __syncthreads();
  }
  int run = (t == 0) ? 0 : sums[t - 1];
  for (int k = 0; k < CH; ++k) {
    int i = base + k;
    if (i < NN) {
      rowstart[i] = run;
      cursor[i]   = run;
      run += cnt[i];
    }
  }
  if (t == 255) rowstart[NN] = run;   // == NE
}

// ---- scatter edges into destination-CSR slots; precompute norm weight ----
__global__ __launch_bounds__(256) void k_scatter(const int* __restrict__ er,
                                                 const int* __restrict__ ec,
                                                 const float* __restrict__ ew,
                                                 const float* __restrict__ dinv,
                                                 int* __restrict__ cursor,
                                                 int* __restrict__ csr_src,
                                                 float* __restrict__ csr_w) {
  int e = blockIdx.x*256 + threadIdx.x;
  if (e < NE) {
    int r = er[e], c = ec[e];
    int slot = atomicAdd(&cursor[c], 1);
    csr_src[slot] = r;
    csr_w[slot]   = dinv[r] * ew[e] * dinv[c];
  }
}

// ---- h += x @ W_conv : double-buffered LDS, software-pipelined staging ----
// Per iter: issue next B (global_load_lds) + next A (fp32->reg) FIRST, MFMA on
// current buffer, then convert+ds_write prefetched A. One barrier per iter.
// HBM latency overlaps MFMA + convert (+ the other resident block's work).
__global__ __launch_bounds__(256) void k_gemm(const float* __restrict__ xg,
                                              const unsigned short* __restrict__ Wt,
                                              float* __restrict__ h) {
  __shared__ unsigned short lA[2*128*64];   // 32 KB (2 buffers)
  __shared__ unsigned short lB[2*128*64];   // 32 KB (2 buffers)
  const int tid  = threadIdx.x;
  const int lane = tid & 63;
  const int w    = tid >> 6;
  const int bid  = blockIdx.x;
  const int mt   = bid % MT;
  const int kc   = bid / MT;
  const int m0   = mt * 128;
  const int it0  = (KITERS * kc) / NSPLIT;
  const int it1  = (KITERS * (kc + 1)) / NSPLIT;

  const int srow = tid >> 3;          // 0..31 within each 32-row round
  const int scol = (tid & 7) * 8;     // 0,8,..,56
  const float* pA[4];
  const unsigned short* pB[4];
#pragma unroll
  for (int r = 0; r < 4; ++r) {
    int ga = m0 + r*32 + srow; if (ga > NN-1) ga = NN-1;   // M-tail clamp (rows discarded)
    pA[r] = xg + (size_t)ga * KK + scol;
    pB[r] = Wt + (size_t)(r*32 + srow) * KPAD + scol;
  }

  f32x16 acc[4];
#pragma unroll
  for (int ct = 0; ct < 4; ++ct)
#pragma unroll
    for (int q = 0; q < 16; ++q) acc[ct][q] = 0.0f;

  float4 fA[4][2];                    // A prefetch registers (32 VGPRs)

#define ISSUE_B(K0, SEL)                                                          \
  _Pragma("unroll")                                                               \
  for (int r = 0; r < 4; ++r) {                                                   \
    __builtin_amdgcn_global_load_lds(                                             \
        (const __attribute__((address_space(1))) unsigned int*)(pB[r] + (K0)),    \
        (__attribute__((address_space(3))) unsigned int*)(&lB[(SEL)*8192 + r*2048 + tid*8]), \
        16, 0, 0);                                                                \
  }

#define LOAD_A(K0)                                                                \
  _Pragma("unroll")                                                               \
  for (int r = 0; r < 4; ++r) {                                                   \
    if (((K0) + scol) < KK) {                                                     \
      fA[r][0] = *(const float4*)(pA[r] + (K0));                                  \
      fA[r][1] = *(const float4*)(pA[r] + (K0) + 4);                              \
    } else {                                                                      \
      fA[r][0] = make_float4(0.f,0.f,0.f,0.f);                                    \
      fA[r][1] = make_float4(0.f,0.f,0.f,0.f);                                    \
    }                                                                             \
  }

#define WRITE_A(SEL)                                                              \
  _Pragma("unroll")                                                               \
  for (int r = 0; r < 4; ++r) {                                                   \
    uint4 u;                                                                      \
    u.x = (unsigned)f2bf(fA[r][0].x) | ((unsigned)f2bf(fA[r][0].y) << 16);        \
    u.y = (unsigned)f2bf(fA[r][0].z) | ((unsigned)f2bf(fA[r][0].w) << 16);        \
    u.z = (unsigned)f2bf(fA[r][1].x) | ((unsigned)f2bf(fA[r][1].y) << 16);        \
    u.w = (unsigned)f2bf(fA[r][1].z) | ((unsigned)f2bf(fA[r][1].w) << 16);        \
    *((uint4*)&lA[(SEL)*8192 + r*2048 + tid*8]) = u;                              \
  }

  // prologue: stage tile it0 into buffer 0
  {
    const int k0 = it0 * 64;
    ISSUE_B(k0, 0);
    LOAD_A(k0);
    WRITE_A(0);
  }
  __syncthreads();   // compiler emits vmcnt(0)+lgkmcnt(0): B landed, A written

  for (int it = it0; it < it1; ++it) {
    const int cur = (it - it0) & 1;
    const int nxt = cur ^ 1;
    const bool more = (it + 1) < it1;
    if (more) {
      const int k0n = (it + 1) * 64;
      ISSUE_B(k0n, nxt);     // direct-to-LDS into the other buffer
      LOAD_A(k0n);           // fp32 -> regs; latency hides under MFMA below
    }
    const unsigned short* Arow = &lA[cur*8192 + (w*32 + (lane & 31))*64 + (lane >> 5)*8];
    const unsigned short* Brow = &lB[cur*8192 + ((lane & 31))*64 + (lane >> 5)*8];
#pragma unroll
    for (int s = 0; s < 4; ++s) {
      bf16x8 a = *(const bf16x8*)(Arow + s*16);
#pragma unroll
      for (int ct = 0; ct < 4; ++ct) {
        bf16x8 b = *(const bf16x8*)(Brow + ct*2048 + s*16);
        acc[ct] = __builtin_amdgcn_mfma_f32_32x32x16_bf16(a, b, acc[ct], 0, 0, 0);
      }
    }
    if (more) { WRITE_A(nxt); }   // waits vmcnt for fA, converts, ds_write
    __syncthreads();              // publishes buffer nxt for next iter
  }

  // epilogue: atomic K-split accumulate. C/D layout (measured m74/m101):
  // col=lane&31, row=(reg&3)+8*(reg>>2)+4*(lane>>5)
#pragma unroll
  for (int ct = 0; ct < 4; ++ct) {
    int col = ct*32 + (lane & 31);
#pragma unroll
    for (int reg = 0; reg < 16; ++reg) {
      int rloc = (reg & 3) + 8*(reg >> 2) + 4*(lane >> 5);
      int row = m0 + w*32 + rloc;
      if (row < NN) atomicAdd(&h[(size_t)row*HID + col], acc[ct][reg]);
    }
  }
#undef ISSUE_B
#undef LOAD_A
#undef WRITE_A
}

// ---- fused: CSR gather-aggregate + self-loop + bias + relu + W_lin + softmax ----
// one wave per node; lane owns features (2*lane, 2*lane+1); fp32 register accum
__global__ __launch_bounds__(256) void k_aggout(const int* __restrict__ rowstart,
                                                const int* __restrict__ csr_src,
                                                const float* __restrict__ csr_w,
                                                const float* __restrict__ h,
                                                const float* __restrict__ dinv,
                                                const float* __restrict__ bc,
                                                const float* __restrict__ Wl,
                                                const float* __restrict__ bl,
                                                float* __restrict__ out) {
  int i = blockIdx.x*4 + (threadIdx.x >> 6);
  if (i >= NN) return;
  int lane = threadIdx.x & 63;
  const float* hp = h + 2*lane;        // lane's 8B column slice of each row
  int j  = rowstart[i];
  int j1 = rowstart[i + 1];

  float ax = 0.f, ay = 0.f;
  // unroll-4: 4 independent row gathers in flight against L2/L3 latency
  for (; j + 3 < j1; j += 4) {
    int   s0 = csr_src[j],   s1 = csr_src[j+1], s2 = csr_src[j+2], s3 = csr_src[j+3];
    float w0 = csr_w[j],     w1 = csr_w[j+1],   w2 = csr_w[j+2],   w3 = csr_w[j+3];
    float2 a = *(const float2*)(hp + (size_t)s0*HID);
    float2 b = *(const float2*)(hp + (size_t)s1*HID);
    float2 c = *(const float2*)(hp + (size_t)s2*HID);
    float2 d = *(const float2*)(hp + (size_t)s3*HID);
    ax += w0*a.x + w1*b.x + w2*c.x + w3*d.x;
    ay += w0*a.y + w1*b.y + w2*c.y + w3*d.y;
  }
  for (; j < j1; ++j) {
    int   s0 = csr_src[j];
    float w0 = csr_w[j];
    float2 a = *(const float2*)(hp + (size_t)s0*HID);
    ax += w0*a.x; ay += w0*a.y;
  }

  // self-loop (norm = dinv[i]^2) + bias + relu
  float di = dinv[i], d2 = di*di;
  float2 hs = *(const float2*)(hp + (size_t)i*HID);
  float2 bb = *(const float2*)(bc + 2*lane);
  float v0 = fmaxf(ax + d2*hs.x + bb.x, 0.0f);
  float v1 = fmaxf(ay + d2*hs.y + bb.y, 0.0f);

  // logits: Wl is [128][2] row-major; features 2*lane, 2*lane+1 -> float4 at 4*lane
  float4 w4 = *(const float4*)(Wl + 4*lane);
  float l0 = v0*w4.x + v1*w4.z;
  float l1 = v0*w4.y + v1*w4.w;
#pragma unroll
  for (int off = 32; off > 0; off >>= 1) {
    l0 += __shfl_down(l0, off);
    l1 += __shfl_down(l1, off);
  }
  if (lane == 0) {
    l0 += bl[0]; l1 += bl[1];
    float m  = fmaxf(l0, l1);
    float e0 = expf(l0 - m), e1 = expf(l1 - m);
    float s  = 1.0f / (e0 + e1);
    *(float2*)(out + (size_t)i*2) = make_float2(e0 * s, e1 * s);
  }
}

extern "C" void kernel_launch(void* const* d_in, const int* in_sizes, int n_in,
                              void* d_out, int out_size, void* d_ws, size_t ws_size,
                              hipStream_t stream) {
  (void)in_sizes; (void)n_in; (void)out_size; (void)ws_size;
  const float* x  = (const float*)d_in[0];   // f32 [10000,10000]
  const int*   ei = (const int*)d_in[1];     // int32 or int64 [2,E] (detected)
  const float* ew = (const float*)d_in[2];   // f32 [E]
  const float* Wc = (const float*)d_in[3];   // f32 [10000,128]
  const float* bc = (const float*)d_in[4];   // f32 [128]
  const float* Wl = (const float*)d_in[5];   // f32 [128,2]
  const float* bl = (const float*)d_in[6];   // f32 [2]

  char* ws = (char*)d_ws;
  float* dinv = (float*)(ws + OFF_DINV);
  int*   flag = (int*)(ws + OFF_FLAG);
  int*   cnt  = (int*)(ws + OFF_CNT);
  int*   row  = (int*)(ws + OFF_ROW);
  int*   cur  = (int*)(ws + OFF_CUR);
  int*   er   = (int*)(ws + OFF_ER);
  int*   ec   = (int*)(ws + OFF_EC);
  int*   csrs = (int*)(ws + OFF_CSRS);
  float* csrw = (float*)(ws + OFF_CSRW);
  float* h    = (float*)(ws + OFF_H);
  unsigned short* Wt = (unsigned short*)(ws + OFF_WT);
  float* out = (float*)d_out;

  hipMemsetAsync(dinv, 0, NN*sizeof(float), stream);
  hipMemsetAsync(cnt,  0, NN*sizeof(int),   stream);
  hipMemsetAsync(h,    0, (size_t)NN*HID*sizeof(float), stream);

  k_detect<<<1, 64, 0, stream>>>(ei, flag);
  k_edges <<<(NE + 255)/256, 256, 0, stream>>>(ei, flag, ew, er, ec, dinv, cnt);
  k_transpose<<<dim3(KPAD/32, HID/32), dim3(32, 8), 0, stream>>>(Wc, Wt);
  k_dinv<<<(NN + 255)/256, 256, 0, stream>>>(dinv);
  k_scan<<<1, 256, 0, stream>>>(cnt, row, cur);
  k_scatter<<<(NE + 255)/256, 256, 0, stream>>>(er, ec, ew, dinv, cur, csrs, csrw);
  k_gemm<<<MT*NSPLIT, 256, 0, stream>>>(x, Wt, h);
  k_aggout<<<NN/4, 256, 0, stream>>>(row, csrs, csrw, h, dinv, bc, Wl, bl, out);
}

// Round 4
// 696.491 us; speedup vs baseline: 1.0957x; 1.0957x over previous
//
#include <hip/hip_runtime.h>
#include <hip/hip_bf16.h>
#include <math.h>

// Problem constants (from reference)
#define NN   10000      // nodes
#define NE   320000     // edges
#define KK   10000      // input features
#define HID  128
#define KPAD 10048      // 157*64, zero-padded K for Wt
#define MT   79         // ceil(10000/128) M-tiles
#define KITERS 157      // ceil(10000/64)
#define NSPLIT 8        // K-split for GEMM grid

typedef __bf16 bf16x8 __attribute__((ext_vector_type(8)));
typedef float  f32x16 __attribute__((ext_vector_type(16)));

// ---- workspace layout (bytes), total ~16.2 MB ----
#define OFF_DINV 0u             // 40000 B (deg, then dinv in place)
#define OFF_FLAG 40960u         // 4 B (edge-index dtype flag)
#define OFF_CNT  45056u         // 40000 B int in-degree counts
#define OFF_ROW  86016u         // 40004 B rowstart[NN+1]
#define OFF_CUR  126976u        // 40000 B scatter cursors
#define OFF_ER   262144u        // 1.28 MB src (int32)
#define OFF_EC   1572864u       // 1.28 MB dst (int32)
#define OFF_CSRS 2883584u       // 1.28 MB CSR src node per slot
#define OFF_CSRW 4194304u       // 1.28 MB CSR norm weight per slot
#define OFF_H    8388608u       // 10000*128 f32 = 5.12 MB
#define OFF_WT   13631488u      // 128*10048 bf16 = 2.57 MB

__device__ inline unsigned short f2bf(float f) {
  unsigned int v = __builtin_bit_cast(unsigned int, f);
  unsigned int lsb = (v >> 16) & 1u;
  v += 0x7fffu + lsb;                 // round-to-nearest-even
  return (unsigned short)(v >> 16);
}

// ---- detect edge_index storage width: int64 => all high words zero ----
__global__ __launch_bounds__(64) void k_detect(const int* __restrict__ ei,
                                               int* __restrict__ flag) {
  int t = threadIdx.x;                 // 64 threads
  int v = ei[2*t + 1];                 // high word if int64, else a real index
  unsigned long long b = __ballot(v != 0);
  if (t == 0) flag[0] = (b == 0ull) ? 1 : 0;
}

// ---- normalize edge_index to int32 er/ec; fused weighted-degree + count ----
__global__ __launch_bounds__(256) void k_edges(const int* __restrict__ ei,
                                               const int* __restrict__ flag,
                                               const float* __restrict__ ew,
                                               int* __restrict__ er,
                                               int* __restrict__ ec,
                                               float* __restrict__ deg,
                                               int* __restrict__ cnt) {
  int e = blockIdx.x*256 + threadIdx.x;
  if (e < NE) {
    int s = flag[0];
    int r = ei[(size_t)e << s];
    int c = ei[((size_t)(NE + e)) << s];
    er[e] = r;
    ec[e] = c;
    atomicAdd(&deg[c], ew[e]);
    atomicAdd(&cnt[c], 1);
  }
}

// ---- transpose + convert + zero-pad W_conv [KK][HID] f32 -> Wt [HID][KPAD] bf16 ----
__global__ __launch_bounds__(256) void k_transpose(const float* __restrict__ W,
                                                   unsigned short* __restrict__ Wt) {
  __shared__ float t[32][33];
  const int tx = threadIdx.x, ty = threadIdx.y;
  const int bk = blockIdx.x, bn = blockIdx.y;
#pragma unroll
  for (int j = 0; j < 4; ++j) {
    int k = bk*32 + ty + j*8;
    int n = bn*32 + tx;
    float v = 0.0f;
    if (k < KK) v = W[(size_t)k*HID + n];
    t[ty + j*8][tx] = v;
  }
  __syncthreads();
#pragma unroll
  for (int j = 0; j < 4; ++j) {
    int n = bn*32 + ty + j*8;
    int k = bk*32 + tx;
    Wt[(size_t)n*KPAD + k] = f2bf(t[tx][ty + j*8]);
  }
}

// ---- fused: dinv transform + exclusive scan of cnt -> rowstart/cursor ----
__global__ __launch_bounds__(256) void k_scan(const int* __restrict__ cnt,
                                              int* __restrict__ rowstart,
                                              int* __restrict__ cursor,
                                              float* __restrict__ deg) {
  __shared__ int sums[256];
  const int t = threadIdx.x;
  const int CH = 40;                  // 256*40 = 10240 >= NN
  const int base = t * CH;
  // dinv in place (self-loop weight 1 added); independent of scan below
  for (int k = 0; k < CH; ++k) {
    int i = base + k;
    if (i < NN) {
      float d = deg[i] + 1.0f;
      deg[i] = (d > 0.0f) ? (1.0f / sqrtf(d)) : 0.0f;
    }
  }
  int s = 0;
  for (int k = 0; k < CH; ++k) {
    int i = base + k;
    if (i < NN) s += cnt[i];
  }
  sums[t] = s;
  __syncthreads();
  // Hillis-Steele inclusive scan over per-thread sums
  for (int off = 1; off < 256; off <<= 1) {
    int add = (t >= off) ? sums[t - off] : 0;
    __syncthreads();
    sums[t] += add;
    __syncthreads();
  }
  int run = (t == 0) ? 0 : sums[t - 1];
  for (int k = 0; k < CH; ++k) {
    int i = base + k;
    if (i < NN) {
      rowstart[i] = run;
      cursor[i]   = run;
      run += cnt[i];
    }
  }
  if (t == 255) rowstart[NN] = run;   // == NE
}

// ---- scatter edges into destination-CSR slots; precompute norm weight ----
__global__ __launch_bounds__(256) void k_scatter(const int* __restrict__ er,
                                                 const int* __restrict__ ec,
                                                 const float* __restrict__ ew,
                                                 const float* __restrict__ dinv,
                                                 int* __restrict__ cursor,
                                                 int* __restrict__ csr_src,
                                                 float* __restrict__ csr_w) {
  int e = blockIdx.x*256 + threadIdx.x;
  if (e < NE) {
    int r = er[e], c = ec[e];
    int slot = atomicAdd(&cursor[c], 1);
    csr_src[slot] = r;
    csr_w[slot]   = dinv[r] * ew[e] * dinv[c];
  }
}

// ---- h += x @ W_conv : single-buffer staging, T2 XOR-swizzled LDS ----
// Rows of lA/lB are 64 bf16 = 128 B = exactly 32 banks, so un-swizzled fragment
// reads put 32 lanes on one 16B chunk column (4x over LDS BW floor). Swizzle:
// chunk' = chunk ^ (row&7), applied on A ds_write + both ds_read sides, and on
// B via pre-swizzled GLOBAL source (global_load_lds dest must stay linear, #21).
__global__ __launch_bounds__(256) void k_gemm(const float* __restrict__ xg,
                                              const unsigned short* __restrict__ Wt,
                                              float* __restrict__ h) {
  __shared__ unsigned short lA[128*64];   // 16 KB
  __shared__ unsigned short lB[128*64];   // 16 KB
  const int tid  = threadIdx.x;
  const int lane = tid & 63;
  const int w    = tid >> 6;
  const int bid  = blockIdx.x;
  const int mt   = bid % MT;
  const int kc   = bid / MT;
  const int m0   = mt * 128;
  const int it0  = (KITERS * kc) / NSPLIT;
  const int it1  = (KITERS * (kc + 1)) / NSPLIT;

  const int srow  = tid >> 3;           // 0..31 within each 32-row round
  const int chunk = tid & 7;            // 16B chunk index within 128B row
  const int swz   = chunk ^ (srow & 7); // swizzled chunk
  const int scol  = chunk * 8;          // natural k offset (elements) for A load

  const float* pA[4];
  const unsigned short* pB[4];
#pragma unroll
  for (int r = 0; r < 4; ++r) {
    int ga = m0 + r*32 + srow; if (ga > NN-1) ga = NN-1;   // M-tail clamp (rows discarded)
    pA[r] = xg + (size_t)ga * KK + scol;                   // natural source chunk
    pB[r] = Wt + (size_t)(r*32 + srow) * KPAD + swz*8;     // pre-swizzled source chunk
  }

  f32x16 acc[4];
#pragma unroll
  for (int ct = 0; ct < 4; ++ct)
#pragma unroll
    for (int q = 0; q < 16; ++q) acc[ct][q] = 0.0f;

  // fragment-read offsets (shorts) within a row band, swizzle folded in:
  // logical chunk for k-step s = (lane>>5) + 2*s; row&7 == lane&7 for all reads
  int co[4];
#pragma unroll
  for (int s = 0; s < 4; ++s)
    co[s] = ((((lane >> 5) + 2*s) ^ (lane & 7)) << 3);

  for (int it = it0; it < it1; ++it) {
    const int k0 = it * 64;
    __syncthreads();
    // B tile: bf16, zero-padded to KPAD -> always in-bounds, direct-to-LDS
    // (linear dest + pre-swizzled global source = swizzled layout in LDS)
#pragma unroll
    for (int r = 0; r < 4; ++r) {
      __builtin_amdgcn_global_load_lds(
          (const __attribute__((address_space(1))) unsigned int*)(pB[r] + k0),
          (__attribute__((address_space(3))) unsigned int*)(&lB[r*2048 + tid*8]),
          16, 0, 0);
    }
    // A tile: fp32 load -> bf16 convert -> swizzled ds_write_b128
    // KK%8==0 so each 8-wide chunk is fully in- or out-of-bounds
#pragma unroll
    for (int r = 0; r < 4; ++r) {
      float4 f0 = make_float4(0.f,0.f,0.f,0.f), f1 = f0;
      if ((k0 + scol) < KK) {
        f0 = *(const float4*)(pA[r] + k0);
        f1 = *(const float4*)(pA[r] + k0 + 4);
      }
      uint4 u;
      u.x = (unsigned)f2bf(f0.x) | ((unsigned)f2bf(f0.y) << 16);
      u.y = (unsigned)f2bf(f0.z) | ((unsigned)f2bf(f0.w) << 16);
      u.z = (unsigned)f2bf(f1.x) | ((unsigned)f2bf(f1.y) << 16);
      u.w = (unsigned)f2bf(f1.z) | ((unsigned)f2bf(f1.w) << 16);
      *((uint4*)&lA[(r*32 + srow)*64 + swz*8]) = u;
    }
    __syncthreads();

    const unsigned short* Aband = &lA[(w*32 + (lane & 31))*64];
    const unsigned short* Bband = &lB[(lane & 31)*64];
#pragma unroll
    for (int s = 0; s < 4; ++s) {
      bf16x8 a = *(const bf16x8*)(Aband + co[s]);
#pragma unroll
      for (int ct = 0; ct < 4; ++ct) {
        bf16x8 b = *(const bf16x8*)(Bband + ct*2048 + co[s]);
        acc[ct] = __builtin_amdgcn_mfma_f32_32x32x16_bf16(a, b, acc[ct], 0, 0, 0);
      }
    }
  }

  // epilogue: atomic K-split accumulate. C/D layout (measured m74/m101):
  // col=lane&31, row=(reg&3)+8*(reg>>2)+4*(lane>>5)
#pragma unroll
  for (int ct = 0; ct < 4; ++ct) {
    int col = ct*32 + (lane & 31);
#pragma unroll
    for (int reg = 0; reg < 16; ++reg) {
      int rloc = (reg & 3) + 8*(reg >> 2) + 4*(lane >> 5);
      int row = m0 + w*32 + rloc;
      if (row < NN) atomicAdd(&h[(size_t)row*HID + col], acc[ct][reg]);
    }
  }
}

// ---- fused: CSR gather-aggregate + self-loop + bias + relu + W_lin + softmax ----
// one wave per node; lane owns features (2*lane, 2*lane+1); fp32 register accum
__global__ __launch_bounds__(256) void k_aggout(const int* __restrict__ rowstart,
                                                const int* __restrict__ csr_src,
                                                const float* __restrict__ csr_w,
                                                const float* __restrict__ h,
                                                const float* __restrict__ dinv,
                                                const float* __restrict__ bc,
                                                const float* __restrict__ Wl,
                                                const float* __restrict__ bl,
                                                float* __restrict__ out) {
  int i = blockIdx.x*4 + (threadIdx.x >> 6);
  if (i >= NN) return;
  int lane = threadIdx.x & 63;
  const float* hp = h + 2*lane;        // lane's 8B column slice of each row
  int j  = rowstart[i];
  int j1 = rowstart[i + 1];

  float ax = 0.f, ay = 0.f;
  // unroll-4: 4 independent row gathers in flight against L2/L3 latency
  for (; j + 3 < j1; j += 4) {
    int   s0 = csr_src[j],   s1 = csr_src[j+1], s2 = csr_src[j+2], s3 = csr_src[j+3];
    float w0 = csr_w[j],     w1 = csr_w[j+1],   w2 = csr_w[j+2],   w3 = csr_w[j+3];
    float2 a = *(const float2*)(hp + (size_t)s0*HID);
    float2 b = *(const float2*)(hp + (size_t)s1*HID);
    float2 c = *(const float2*)(hp + (size_t)s2*HID);
    float2 d = *(const float2*)(hp + (size_t)s3*HID);
    ax += w0*a.x + w1*b.x + w2*c.x + w3*d.x;
    ay += w0*a.y + w1*b.y + w2*c.y + w3*d.y;
  }
  for (; j < j1; ++j) {
    int   s0 = csr_src[j];
    float w0 = csr_w[j];
    float2 a = *(const float2*)(hp + (size_t)s0*HID);
    ax += w0*a.x; ay += w0*a.y;
  }

  // self-loop (norm = dinv[i]^2) + bias + relu
  float di = dinv[i], d2 = di*di;
  float2 hs = *(const float2*)(hp + (size_t)i*HID);
  float2 bb = *(const float2*)(bc + 2*lane);
  float v0 = fmaxf(ax + d2*hs.x + bb.x, 0.0f);
  float v1 = fmaxf(ay + d2*hs.y + bb.y, 0.0f);

  // logits: Wl is [128][2] row-major; features 2*lane, 2*lane+1 -> float4 at 4*lane
  float4 w4 = *(const float4*)(Wl + 4*lane);
  float l0 = v0*w4.x + v1*w4.z;
  float l1 = v0*w4.y + v1*w4.w;
#pragma unroll
  for (int off = 32; off > 0; off >>= 1) {
    l0 += __shfl_down(l0, off);
    l1 += __shfl_down(l1, off);
  }
  if (lane == 0) {
    l0 += bl[0]; l1 += bl[1];
    float m  = fmaxf(l0, l1);
    float e0 = expf(l0 - m), e1 = expf(l1 - m);
    float s  = 1.0f / (e0 + e1);
    *(float2*)(out + (size_t)i*2) = make_float2(e0 * s, e1 * s);
  }
}

extern "C" void kernel_launch(void* const* d_in, const int* in_sizes, int n_in,
                              void* d_out, int out_size, void* d_ws, size_t ws_size,
                              hipStream_t stream) {
  (void)in_sizes; (void)n_in; (void)out_size; (void)ws_size;
  const float* x  = (const float*)d_in[0];   // f32 [10000,10000]
  const int*   ei = (const int*)d_in[1];     // int32 or int64 [2,E] (detected)
  const float* ew = (const float*)d_in[2];   // f32 [E]
  const float* Wc = (const float*)d_in[3];   // f32 [10000,128]
  const float* bc = (const float*)d_in[4];   // f32 [128]
  const float* Wl = (const float*)d_in[5];   // f32 [128,2]
  const float* bl = (const float*)d_in[6];   // f32 [2]

  char* ws = (char*)d_ws;
  float* dinv = (float*)(ws + OFF_DINV);
  int*   flag = (int*)(ws + OFF_FLAG);
  int*   cnt  = (int*)(ws + OFF_CNT);
  int*   row  = (int*)(ws + OFF_ROW);
  int*   cur  = (int*)(ws + OFF_CUR);
  int*   er   = (int*)(ws + OFF_ER);
  int*   ec   = (int*)(ws + OFF_EC);
  int*   csrs = (int*)(ws + OFF_CSRS);
  float* csrw = (float*)(ws + OFF_CSRW);
  float* h    = (float*)(ws + OFF_H);
  unsigned short* Wt = (unsigned short*)(ws + OFF_WT);
  float* out = (float*)d_out;

  hipMemsetAsync(dinv, 0, NN*sizeof(float), stream);
  hipMemsetAsync(cnt,  0, NN*sizeof(int),   stream);
  hipMemsetAsync(h,    0, (size_t)NN*HID*sizeof(float), stream);

  k_detect<<<1, 64, 0, stream>>>(ei, flag);
  k_edges <<<(NE + 255)/256, 256, 0, stream>>>(ei, flag, ew, er, ec, dinv, cnt);
  k_transpose<<<dim3(KPAD/32, HID/32), dim3(32, 8), 0, stream>>>(Wc, Wt);
  k_scan<<<1, 256, 0, stream>>>(cnt, row, cur, dinv);
  k_scatter<<<(NE + 255)/256, 256, 0, stream>>>(er, ec, ew, dinv, cur, csrs, csrw);
  k_gemm<<<MT*NSPLIT, 256, 0, stream>>>(x, Wt, h);
  k_aggout<<<NN/4, 256, 0, stream>>>(row, csrs, csrw, h, dinv, bc, Wl, bl, out);
}

// Round 5
// 673.291 us; speedup vs baseline: 1.1335x; 1.0345x over previous
//
#include <hip/hip_runtime.h>
#include <hip/hip_bf16.h>
#include <math.h>

// Problem constants (from reference)
#define NN   10000      // nodes
#define NE   320000     // edges
#define KK   10000      // input features
#define HID  128
#define KPAD 10048      // 157*64, zero-padded K for Wt
#define MT   79         // ceil(10000/128) M-tiles
#define KITERS 157      // ceil(10000/64)
#define NSPLIT 8        // K-split for GEMM grid

typedef __bf16 bf16x8 __attribute__((ext_vector_type(8)));
typedef float  f32x16 __attribute__((ext_vector_type(16)));

// ---- workspace layout (bytes), total ~16.2 MB ----
#define OFF_DEG  0u             // 40000 B raw weighted degree (never transformed)
#define OFF_CNT  45056u         // 40000 B int in-degree counts
#define OFF_ROW  86016u         // 40004 B rowstart[NN+1]
#define OFF_CUR  126976u        // 40000 B scatter cursors
#define OFF_ER   262144u        // 1.28 MB src (int32)
#define OFF_EC   1572864u       // 1.28 MB dst (int32)
#define OFF_CSRS 2883584u       // 1.28 MB CSR src node per slot
#define OFF_CSRW 4194304u       // 1.28 MB CSR norm weight per slot
#define OFF_H    8388608u       // 10000*128 f32 = 5.12 MB
#define OFF_WT   13631488u      // 128*10048 bf16 = 2.57 MB

__device__ inline unsigned short f2bf(float f) {
  unsigned int v = __builtin_bit_cast(unsigned int, f);
  unsigned int lsb = (v >> 16) & 1u;
  v += 0x7fffu + lsb;                 // round-to-nearest-even
  return (unsigned short)(v >> 16);
}

// ---- normalize edge_index to int32 er/ec; per-block dtype detect (wave-0
// ballot over first 64 high words); fused weighted-degree + count ----
__global__ __launch_bounds__(256) void k_edges(const int* __restrict__ ei,
                                               const float* __restrict__ ew,
                                               int* __restrict__ er,
                                               int* __restrict__ ec,
                                               float* __restrict__ deg,
                                               int* __restrict__ cnt) {
  __shared__ int sflag;
  const int t = threadIdx.x;
  if (t < 64) {                       // wave 0, fully active
    int v = ei[2*t + 1];              // high word if int64, else a real index
    unsigned long long b = __ballot(v != 0);
    if (t == 0) sflag = (b == 0ull) ? 1 : 0;
  }
  __syncthreads();
  const int s = sflag;
  int e = blockIdx.x*256 + t;
  if (e < NE) {
    int r = ei[(size_t)e << s];
    int c = ei[((size_t)(NE + e)) << s];
    er[e] = r;
    ec[e] = c;
    atomicAdd(&deg[c], ew[e]);
    atomicAdd(&cnt[c], 1);
  }
}

// ---- transpose + convert + zero-pad W_conv [KK][HID] f32 -> Wt [HID][KPAD] bf16 ----
__global__ __launch_bounds__(256) void k_transpose(const float* __restrict__ W,
                                                   unsigned short* __restrict__ Wt) {
  __shared__ float t[32][33];
  const int tx = threadIdx.x, ty = threadIdx.y;
  const int bk = blockIdx.x, bn = blockIdx.y;
#pragma unroll
  for (int j = 0; j < 4; ++j) {
    int k = bk*32 + ty + j*8;
    int n = bn*32 + tx;
    float v = 0.0f;
    if (k < KK) v = W[(size_t)k*HID + n];
    t[ty + j*8][tx] = v;
  }
  __syncthreads();
#pragma unroll
  for (int j = 0; j < 4; ++j) {
    int n = bn*32 + ty + j*8;
    int k = bk*32 + tx;
    Wt[(size_t)n*KPAD + k] = f2bf(t[tx][ty + j*8]);
  }
}

// ---- single-block exclusive scan of cnt[NN] -> rowstart[NN+1], cursor copy ----
// 1024 threads, CH=10: 4x less serial per-thread work than the 256-thread version
__global__ __launch_bounds__(1024) void k_scan(const int* __restrict__ cnt,
                                               int* __restrict__ rowstart,
                                               int* __restrict__ cursor) {
  __shared__ int sums[1024];
  const int t = threadIdx.x;
  const int CH = 10;                  // 1024*10 = 10240 >= NN
  const int base = t * CH;
  int s = 0;
#pragma unroll
  for (int k = 0; k < CH; ++k) {
    int i = base + k;
    if (i < NN) s += cnt[i];
  }
  sums[t] = s;
  __syncthreads();
  // Hillis-Steele inclusive scan over per-thread sums
  for (int off = 1; off < 1024; off <<= 1) {
    int add = (t >= off) ? sums[t - off] : 0;
    __syncthreads();
    sums[t] += add;
    __syncthreads();
  }
  int run = (t == 0) ? 0 : sums[t - 1];
#pragma unroll
  for (int k = 0; k < CH; ++k) {
    int i = base + k;
    if (i < NN) {
      rowstart[i] = run;
      cursor[i]   = run;
      run += cnt[i];
    }
  }
  if (t == 1023) rowstart[NN] = run;  // == NE (threads >=1000 add nothing)
}

// ---- scatter edges into destination-CSR slots; norm computed from raw deg ----
__global__ __launch_bounds__(256) void k_scatter(const int* __restrict__ er,
                                                 const int* __restrict__ ec,
                                                 const float* __restrict__ ew,
                                                 const float* __restrict__ deg,
                                                 int* __restrict__ cursor,
                                                 int* __restrict__ csr_src,
                                                 float* __restrict__ csr_w) {
  int e = blockIdx.x*256 + threadIdx.x;
  if (e < NE) {
    int r = er[e], c = ec[e];
    float dr = deg[r] + 1.0f, dc = deg[c] + 1.0f;   // self-loop weight 1
    float ir = (dr > 0.0f) ? (1.0f / sqrtf(dr)) : 0.0f;
    float ic = (dc > 0.0f) ? (1.0f / sqrtf(dc)) : 0.0f;
    int slot = atomicAdd(&cursor[c], 1);
    csr_src[slot] = r;
    csr_w[slot]   = ir * ew[e] * ic;
  }
}

// ---- h += x @ W_conv : A direct global->reg (no LDS — zero cross-wave reuse),
// B double-buffered in LDS via global_load_lds, ONE barrier per K-iter.
// Each lane loads its own MFMA A-fragment: row m0+w*32+(lane&31),
// k = k0 + s*16 + (lane>>5)*8 (8 fp32 = 32B contiguous; 256B/row/iter, L1
// absorbs the sector split across lanes). fp32->bf16 convert in regs (same f2bf).
__global__ __launch_bounds__(256, 3) void k_gemm(const float* __restrict__ xg,
                                                 const unsigned short* __restrict__ Wt,
                                                 float* __restrict__ h) {
  __shared__ unsigned short lB[2*128*64];   // 32 KB (2 buffers)
  const int tid  = threadIdx.x;
  const int lane = tid & 63;
  const int w    = tid >> 6;
  const int bid  = blockIdx.x;
  const int mt   = bid % MT;
  const int kc   = bid / MT;
  const int m0   = mt * 128;
  const int it0  = (KITERS * kc) / NSPLIT;
  const int it1  = (KITERS * (kc + 1)) / NSPLIT;

  // B staging: same pre-swizzled-source scheme as before (linear LDS dest, #21)
  const int srow  = tid >> 3;           // 0..31 within each 32-row round
  const int chunk = tid & 7;            // 16B chunk index within 128B row
  const int swz   = chunk ^ (srow & 7); // swizzled chunk
  const unsigned short* pB[4];
#pragma unroll
  for (int r = 0; r < 4; ++r)
    pB[r] = Wt + (size_t)(r*32 + srow) * KPAD + swz*8;

  // A per-lane fragment base
  int arow = m0 + w*32 + (lane & 31);
  if (arow > NN-1) arow = NN-1;         // M-tail clamp (rows discarded at epilogue)
  const int hi = lane >> 5;
  const float* pa = xg + (size_t)arow * KK + hi*8;

  f32x16 acc[4];
#pragma unroll
  for (int ct = 0; ct < 4; ++ct)
#pragma unroll
    for (int q = 0; q < 16; ++q) acc[ct][q] = 0.0f;

  // B fragment-read offsets (shorts), swizzle folded in (row&7 == lane&7)
  int co[4];
#pragma unroll
  for (int s = 0; s < 4; ++s)
    co[s] = (((hi + 2*s) ^ (lane & 7)) << 3);

#define ISSUE_B(K0, SEL)                                                          \
  _Pragma("unroll")                                                               \
  for (int r = 0; r < 4; ++r) {                                                   \
    __builtin_amdgcn_global_load_lds(                                             \
        (const __attribute__((address_space(1))) unsigned int*)(pB[r] + (K0)),    \
        (__attribute__((address_space(3))) unsigned int*)(&lB[(SEL)*8192 + r*2048 + tid*8]), \
        16, 0, 0);                                                                \
  }

  // prologue: B(it0) -> buf0
  ISSUE_B(it0*64, 0);
  int nbuf = 1;

  for (int it = it0; it < it1; ++it) {
    __syncthreads();                  // B(it) landed (vmcnt0); prev buf reads done (lgkm0)
    const int cur = nbuf ^ 1;         // buffer holding B(it)
    if (it + 1 < it1) { ISSUE_B((it+1)*64, nbuf); }   // L2 latency hides under below
    const int k0 = it * 64;

    // A fragments: global -> reg -> bf16
    bf16x8 af[4];
#pragma unroll
    for (int s = 0; s < 4; ++s) {
      const int col = k0 + s*16 + hi*8;     // multiple of 8; KK%8==0
      float4 f0 = make_float4(0.f,0.f,0.f,0.f), f1 = f0;
      if (col < KK) {
        f0 = *(const float4*)(pa + k0 + s*16);
        f1 = *(const float4*)(pa + k0 + s*16 + 4);
      }
      uint4 u;
      u.x = (unsigned)f2bf(f0.x) | ((unsigned)f2bf(f0.y) << 16);
      u.y = (unsigned)f2bf(f0.z) | ((unsigned)f2bf(f0.w) << 16);
      u.z = (unsigned)f2bf(f1.x) | ((unsigned)f2bf(f1.y) << 16);
      u.w = (unsigned)f2bf(f1.z) | ((unsigned)f2bf(f1.w) << 16);
      af[s] = __builtin_bit_cast(bf16x8, u);
    }

    const unsigned short* Bband = &lB[cur*8192 + (lane & 31)*64];
#pragma unroll
    for (int s = 0; s < 4; ++s) {
      bf16x8 a = af[s];
#pragma unroll
      for (int ct = 0; ct < 4; ++ct) {
        bf16x8 b = *(const bf16x8*)(Bband + ct*2048 + co[s]);
        acc[ct] = __builtin_amdgcn_mfma_f32_32x32x16_bf16(a, b, acc[ct], 0, 0, 0);
      }
    }
    nbuf ^= 1;
  }
#undef ISSUE_B

  // epilogue: atomic K-split accumulate. C/D layout (measured m74/m101):
  // col=lane&31, row=(reg&3)+8*(reg>>2)+4*(lane>>5)
#pragma unroll
  for (int ct = 0; ct < 4; ++ct) {
    int col = ct*32 + (lane & 31);
#pragma unroll
    for (int reg = 0; reg < 16; ++reg) {
      int rloc = (reg & 3) + 8*(reg >> 2) + 4*(lane >> 5);
      int row = m0 + w*32 + rloc;
      if (row < NN) atomicAdd(&h[(size_t)row*HID + col], acc[ct][reg]);
    }
  }
}

// ---- fused: CSR gather-aggregate + self-loop + bias + relu + W_lin + softmax ----
// one wave per node; lane owns features (2*lane, 2*lane+1); fp32 register accum
__global__ __launch_bounds__(256) void k_aggout(const int* __restrict__ rowstart,
                                                const int* __restrict__ csr_src,
                                                const float* __restrict__ csr_w,
                                                const float* __restrict__ h,
                                                const float* __restrict__ deg,
                                                const float* __restrict__ bc,
                                                const float* __restrict__ Wl,
                                                const float* __restrict__ bl,
                                                float* __restrict__ out) {
  int i = blockIdx.x*4 + (threadIdx.x >> 6);
  if (i >= NN) return;
  int lane = threadIdx.x & 63;
  const float* hp = h + 2*lane;        // lane's 8B column slice of each row
  int j  = rowstart[i];
  int j1 = rowstart[i + 1];

  float ax = 0.f, ay = 0.f;
  // unroll-4: 4 independent row gathers in flight against L2/L3 latency
  for (; j + 3 < j1; j += 4) {
    int   s0 = csr_src[j],   s1 = csr_src[j+1], s2 = csr_src[j+2], s3 = csr_src[j+3];
    float w0 = csr_w[j],     w1 = csr_w[j+1],   w2 = csr_w[j+2],   w3 = csr_w[j+3];
    float2 a = *(const float2*)(hp + (size_t)s0*HID);
    float2 b = *(const float2*)(hp + (size_t)s1*HID);
    float2 c = *(const float2*)(hp + (size_t)s2*HID);
    float2 d = *(const float2*)(hp + (size_t)s3*HID);
    ax += w0*a.x + w1*b.x + w2*c.x + w3*d.x;
    ay += w0*a.y + w1*b.y + w2*c.y + w3*d.y;
  }
  for (; j < j1; ++j) {
    int   s0 = csr_src[j];
    float w0 = csr_w[j];
    float2 a = *(const float2*)(hp + (size_t)s0*HID);
    ax += w0*a.x; ay += w0*a.y;
  }

  // self-loop (norm = 1/(deg+1)) + bias + relu
  float d2 = 1.0f / (deg[i] + 1.0f);
  float2 hs = *(const float2*)(hp + (size_t)i*HID);
  float2 bb = *(const float2*)(bc + 2*lane);
  float v0 = fmaxf(ax + d2*hs.x + bb.x, 0.0f);
  float v1 = fmaxf(ay + d2*hs.y + bb.y, 0.0f);

  // logits: Wl is [128][2] row-major; features 2*lane, 2*lane+1 -> float4 at 4*lane
  float4 w4 = *(const float4*)(Wl + 4*lane);
  float l0 = v0*w4.x + v1*w4.z;
  float l1 = v0*w4.y + v1*w4.w;
#pragma unroll
  for (int off = 32; off > 0; off >>= 1) {
    l0 += __shfl_down(l0, off);
    l1 += __shfl_down(l1, off);
  }
  if (lane == 0) {
    l0 += bl[0]; l1 += bl[1];
    float m  = fmaxf(l0, l1);
    float e0 = expf(l0 - m), e1 = expf(l1 - m);
    float s  = 1.0f / (e0 + e1);
    *(float2*)(out + (size_t)i*2) = make_float2(e0 * s, e1 * s);
  }
}

extern "C" void kernel_launch(void* const* d_in, const int* in_sizes, int n_in,
                              void* d_out, int out_size, void* d_ws, size_t ws_size,
                              hipStream_t stream) {
  (void)in_sizes; (void)n_in; (void)out_size; (void)ws_size;
  const float* x  = (const float*)d_in[0];   // f32 [10000,10000]
  const int*   ei = (const int*)d_in[1];     // int32 or int64 [2,E] (detected)
  const float* ew = (const float*)d_in[2];   // f32 [E]
  const float* Wc = (const float*)d_in[3];   // f32 [10000,128]
  const float* bc = (const float*)d_in[4];   // f32 [128]
  const float* Wl = (const float*)d_in[5];   // f32 [128,2]
  const float* bl = (const float*)d_in[6];   // f32 [2]

  char* ws = (char*)d_ws;
  float* deg  = (float*)(ws + OFF_DEG);
  int*   cnt  = (int*)(ws + OFF_CNT);
  int*   row  = (int*)(ws + OFF_ROW);
  int*   cur  = (int*)(ws + OFF_CUR);
  int*   er   = (int*)(ws + OFF_ER);
  int*   ec   = (int*)(ws + OFF_EC);
  int*   csrs = (int*)(ws + OFF_CSRS);
  float* csrw = (float*)(ws + OFF_CSRW);
  float* h    = (float*)(ws + OFF_H);
  unsigned short* Wt = (unsigned short*)(ws + OFF_WT);
  float* out = (float*)d_out;

  hipMemsetAsync(deg, 0, NN*sizeof(float), stream);
  hipMemsetAsync(cnt, 0, NN*sizeof(int),   stream);
  hipMemsetAsync(h,   0, (size_t)NN*HID*sizeof(float), stream);

  k_edges <<<(NE + 255)/256, 256, 0, stream>>>(ei, ew, er, ec, deg, cnt);
  k_transpose<<<dim3(KPAD/32, HID/32), dim3(32, 8), 0, stream>>>(Wc, Wt);
  k_scan<<<1, 1024, 0, stream>>>(cnt, row, cur);
  k_scatter<<<(NE + 255)/256, 256, 0, stream>>>(er, ec, ew, deg, cur, csrs, csrw);
  k_gemm<<<MT*NSPLIT, 256, 0, stream>>>(x, Wt, h);
  k_aggout<<<NN/4, 256, 0, stream>>>(row, csrs, csrw, h, deg, bc, Wl, bl, out);
}